// Round 9
// baseline (2393.587 us; speedup 1.0000x reference)
//
#include <hip/hip_runtime.h>

#define B_ 64
#define T_ 512
#define D_ 512
#define N_ 1024
#define G_ 4096   // 4*N

typedef _Float16 f16;
typedef __attribute__((ext_vector_type(8))) _Float16 f16x8;
typedef __attribute__((ext_vector_type(4))) _Float16 f16x4;
typedef __attribute__((ext_vector_type(4))) float f32x4_t;
typedef unsigned long long u64;
typedef __attribute__((ext_vector_type(4))) unsigned int u32x4;

static __device__ __forceinline__ f32x4_t mfma16(f16x8 a, f16x8 b, f32x4_t c) {
    return __builtin_amdgcn_mfma_f32_16x16x32_f16(a, b, c, 0, 0, 0);
}

// workspace map (inside first 4MB, overlapping dead WxT)
#define PAYB    262144       // one payload copy: [bg4][64KB] (tag-in-data slots)
#define OFF_TAG 0xC0000      // 3*PAYB; hint tags: 4*256 u32 = 4KB

// ---------------------------------------------------------------------------
// Phase 0: WxT[g][d] = (f16) W[d][g]   (validated R1)
// ---------------------------------------------------------------------------
__global__ __launch_bounds__(256) void k_transpose_wx(const float* __restrict__ W,
                                                      f16* __restrict__ WxT) {
    __shared__ float tile[64][65];
    int bx = blockIdx.x;
    int dt = bx >> 6, gt = bx & 63;
    int d0 = dt * 64, g0 = gt * 64;
    int tid = threadIdx.x;
    for (int e = tid; e < 4096; e += 256) {
        int r = e >> 6, c = e & 63;
        tile[r][c] = W[(size_t)(d0 + r) * G_ + (g0 + c)];
    }
    __syncthreads();
    for (int e = tid; e < 4096; e += 256) {
        int r = e >> 6, c = e & 63;
        WxT[(size_t)(g0 + r) * D_ + (d0 + c)] = (f16)tile[c][r];
    }
}

// ---------------------------------------------------------------------------
// Phase 1: xp[t][g][b] = (f16)( x@Wx + bias )   (validated R1)
// ---------------------------------------------------------------------------
__global__ __launch_bounds__(256, 2) void k_xproj(const float* __restrict__ x,
                                                  const f16* __restrict__ WxT,
                                                  const float* __restrict__ bias,
                                                  f16* __restrict__ xp) {
    __shared__ __align__(16) f16 alds[64 * 512];   // 64 KB
    int t = blockIdx.x;
    int tid = threadIdx.x;
    int w = tid >> 6, l = tid & 63;

    for (int ch = tid; ch < 4096; ch += 256) {
        int b  = ch >> 6;
        int d0 = (ch & 63) << 3;
        const float* px = x + ((size_t)b * T_ + t) * D_ + d0;
        float4 v0 = *(const float4*)px;
        float4 v1 = *(const float4*)(px + 4);
        f16x8 s;
        s[0] = (f16)v0.x; s[1] = (f16)v0.y; s[2] = (f16)v0.z; s[3] = (f16)v0.w;
        s[4] = (f16)v1.x; s[5] = (f16)v1.y; s[6] = (f16)v1.z; s[7] = (f16)v1.w;
        unsigned byteoff = ((unsigned)(b * 512 + d0) * 2u) ^ ((unsigned)(b & 7) << 4);
        *(f16x8*)((char*)alds + byteoff) = s;
    }
    __syncthreads();

    const int gw = w * 1024;
    const int qk = (l >> 4) << 3;
    const int cc = l & 15;

    for (int gtb = 0; gtb < 16; ++gtb) {
        f32x4_t acc[4][4];
        #pragma unroll
        for (int a = 0; a < 4; ++a)
            #pragma unroll
            for (int m = 0; m < 4; ++m) acc[a][m] = f32x4_t{0.f, 0.f, 0.f, 0.f};

        for (int ks = 0; ks < 16; ++ks) {
            f16x8 afr[4];
            #pragma unroll
            for (int mb = 0; mb < 4; ++mb) {
                int b = mb * 16 + cc;
                int d = ks * 32 + qk;
                unsigned byteoff = ((unsigned)(b * 512 + d) * 2u) ^ ((unsigned)(b & 7) << 4);
                afr[mb] = *(const f16x8*)((const char*)alds + byteoff);
            }
            #pragma unroll
            for (int gl = 0; gl < 4; ++gl) {
                int g = gw + (gtb * 4 + gl) * 16 + cc;
                f16x8 bfr = *(const f16x8*)(WxT + (size_t)g * D_ + ks * 32 + qk);
                #pragma unroll
                for (int mb = 0; mb < 4; ++mb)
                    acc[gl][mb] = mfma16(afr[mb], bfr, acc[gl][mb]);
            }
        }
        #pragma unroll
        for (int gl = 0; gl < 4; ++gl) {
            int g = gw + (gtb * 4 + gl) * 16 + cc;
            float bg = bias[g];
            #pragma unroll
            for (int mb = 0; mb < 4; ++mb) {
                int b0 = mb * 16 + ((l >> 4) << 2);
                f16x4 sv;
                sv[0] = (f16)(acc[gl][mb][0] + bg);
                sv[1] = (f16)(acc[gl][mb][1] + bg);
                sv[2] = (f16)(acc[gl][mb][2] + bg);
                sv[3] = (f16)(acc[gl][mb][3] + bg);
                *(f16x4*)(xp + ((size_t)t * G_ + g) * B_ + b0) = sv;
            }
        }
    }
}

// ---------------------------------------------------------------------------
// Phase 2: persistent recurrence. R9:
//  - Wh fragments in REGISTERS (bf[4][8], 128 VGPR): no wlds, no per-step
//    ds_reads, no 3.5e7 bank conflicts. Same mapping as R3's validated LDS.
//  - tag-in-data slots (8B = 2 h + u32 tag, R6-validated layout): payload is
//    self-validating -> producer needs NO vmcnt ack before signaling.
//  - R8's per-wave tags kept as a cheap HINT throttle (4B/lane poll);
//    embedded tags (exact-match == t+1) are the only correctness carrier.
//    Exact-match is ABA-safe: triple buffer + 2-hop closure bounds skew < 3.
// ---------------------------------------------------------------------------
__global__ __launch_bounds__(256, 1) void k_recur9(const float* __restrict__ W,
                                                   const f16* __restrict__ xp,
                                                   char* __restrict__ wsb,
                                                   float* __restrict__ out) {
    __shared__ float pacc[4][4][16][17];        // [kwave][ntile][batch][c15+pad]

    const int wg  = blockIdx.x;
    const int tid = threadIdx.x;
    const int w   = tid >> 6;
    const int l   = tid & 63;
    const int bg  = wg >> 6;
    const int ci  = wg & 63;

    const int lb    = l & 15;
    const int dh    = l >> 4;
    const int nh    = ci * 16 + w * 4 + dh;
    const int bglob = bg * 16 + lb;

    char*     const pay  = wsb;                      // 3 x 256 KB
    unsigned* const tags = (unsigned*)(wsb + OFF_TAG);

    // ---- Wh B-fragments into registers (mapping == R3's validated staging) ----
    f16x8 bf[4][8];
    {
        const int kq = l >> 4, ty = (l >> 2) & 3, dcl = l & 3;
        #pragma unroll
        for (int nt = 0; nt < 4; ++nt) {
            const int gc = ty * 1024 + ci * 16 + nt * 4 + dcl;
            #pragma unroll
            for (int kk = 0; kk < 8; ++kk) {
                #pragma unroll
                for (int i = 0; i < 8; ++i) {
                    int k = (w * 8 + kk) * 32 + kq * 8 + i;
                    bf[nt][kk][i] = (f16)W[(size_t)(D_ + k) * G_ + gc];
                }
            }
        }
    }

    // ---- producer slot addressing (R6-validated tag-in-data layout) ----
    const int nq   = ci * 16 + w * 4;
    const int ksq  = nq >> 5;
    const int lanq = (((nq & 31) >> 3) << 4) | lb;
    const size_t st_off = (size_t)bg * 65536 + (size_t)(ksq * 64 + lanq) * 32
                        + (size_t)(w & 1) * 16 + (size_t)(dh >> 1) * 8;
    const bool   do_st  = ((dh & 1) == 0);

    // ---- consumer addressing: wave w reads k in [256w, 256w+256) ----
    const size_t ld_off = (size_t)bg * 65536 + (size_t)(w * 8 * 64 + l) * 32;

    // hint tags: producer (ci,w) publishes; consumer lane l watches 64w+l
    unsigned* const tag_st = tags + (bg * 256 + ci * 4 + w);
    unsigned* const tag_ld = tags + (bg * 256 + w * 64 + l);

    // ---- init: h_0 = 0 with tag 1 into buf0; hint = 1 (no ack needed) ----
    if (do_st)
        __hip_atomic_store((u64*)(pay + st_off), (u64)1u << 32,
                           __ATOMIC_RELAXED, __HIP_MEMORY_SCOPE_AGENT);
    if (l == 0)
        __hip_atomic_store(tag_st, 1u, __ATOMIC_RELAXED, __HIP_MEMORY_SCOPE_AGENT);
    __syncthreads();

    float cst = 0.f;
    int cur = 0, nxt = 1;

    for (int t = 0; t < T_; ++t) {
        // xp loads: non-temporal, issued early (HBM latency hides under poll)
        const unsigned short* xpp = (const unsigned short*)xp
                                  + (size_t)t * G_ * B_ + bglob;
        f16 xg0 = __builtin_bit_cast(f16, __builtin_nontemporal_load(xpp + (size_t)(0 * 1024 + nh) * B_));
        f16 xg1 = __builtin_bit_cast(f16, __builtin_nontemporal_load(xpp + (size_t)(1 * 1024 + nh) * B_));
        f16 xg2 = __builtin_bit_cast(f16, __builtin_nontemporal_load(xpp + (size_t)(2 * 1024 + nh) * B_));
        f16 xg3 = __builtin_bit_cast(f16, __builtin_nontemporal_load(xpp + (size_t)(3 * 1024 + nh) * B_));

        // ---- hint poll (cheap: one 4B load/lane/round) ----
        {
            const unsigned tgt = (unsigned)(t + 1);
            while (true) {
                unsigned v = __hip_atomic_load(tag_ld, __ATOMIC_RELAXED,
                                               __HIP_MEMORY_SCOPE_AGENT);
                if (__all(v >= tgt)) break;
                __builtin_amdgcn_s_sleep(1);
            }
        }

        // ---- payload load + embedded-tag verify (truth; retry on race) ----
        u32x4 qa[8], qb[8];
        {
            const char* pb = pay + (size_t)cur * PAYB + ld_off;
            const unsigned tg = (unsigned)(t + 1);
            while (true) {
                #pragma unroll
                for (int kk = 0; kk < 8; ++kk) {
                    asm volatile("global_load_dwordx4 %0, %1, off sc0 sc1"
                                 : "=&v"(qa[kk]) : "v"(pb + kk * 2048) : "memory");
                    asm volatile("global_load_dwordx4 %0, %1, off sc0 sc1"
                                 : "=&v"(qb[kk]) : "v"(pb + kk * 2048 + 16) : "memory");
                }
                asm volatile("s_waitcnt vmcnt(0)" ::: "memory");
                bool ok = true;
                #pragma unroll
                for (int kk = 0; kk < 8; ++kk)
                    ok = ok && (qa[kk][1] == tg) && (qa[kk][3] == tg)
                            && (qb[kk][1] == tg) && (qb[kk][3] == tg);
                if (__all(ok)) break;
                __builtin_amdgcn_s_sleep(1);
            }
        }
        __builtin_amdgcn_sched_barrier(0);   // keep MFMA after the wait

        // ---- MFMA: A from verified payload, B from registers ----
        f32x4_t acc[4];
        #pragma unroll
        for (int nt = 0; nt < 4; ++nt) acc[nt] = f32x4_t{0.f, 0.f, 0.f, 0.f};
        #pragma unroll
        for (int kk = 0; kk < 8; ++kk) {
            u32x4 av = { qa[kk][0], qa[kk][2], qb[kk][0], qb[kk][2] };
            f16x8 af = __builtin_bit_cast(f16x8, av);
            #pragma unroll
            for (int nt = 0; nt < 4; ++nt)
                acc[nt] = mfma16(af, bf[nt][kk], acc[nt]);
        }

        // ---- cross-wave K-reduction via LDS ----
        {
            const int r0 = dh << 2;
            #pragma unroll
            for (int nt = 0; nt < 4; ++nt)
                #pragma unroll
                for (int j = 0; j < 4; ++j)
                    pacc[w][nt][r0 + j][l & 15] = acc[nt][j];
        }
        __syncthreads();

        float g0 = pacc[0][w][lb][0 * 4 + dh] + pacc[1][w][lb][0 * 4 + dh]
                 + pacc[2][w][lb][0 * 4 + dh] + pacc[3][w][lb][0 * 4 + dh] + (float)xg0;
        float g1 = pacc[0][w][lb][1 * 4 + dh] + pacc[1][w][lb][1 * 4 + dh]
                 + pacc[2][w][lb][1 * 4 + dh] + pacc[3][w][lb][1 * 4 + dh] + (float)xg1;
        float g2 = pacc[0][w][lb][2 * 4 + dh] + pacc[1][w][lb][2 * 4 + dh]
                 + pacc[2][w][lb][2 * 4 + dh] + pacc[3][w][lb][2 * 4 + dh] + (float)xg2;
        float g3 = pacc[0][w][lb][3 * 4 + dh] + pacc[1][w][lb][3 * 4 + dh]
                 + pacc[2][w][lb][3 * 4 + dh] + pacc[3][w][lb][3 * 4 + dh] + (float)xg3;

        float si = 1.f / (1.f + __expf(-g0));
        float tj = tanhf(g1);
        float sf = 1.f / (1.f + __expf(-(g2 + 1.f)));
        float so = 1.f / (1.f + __expf(-g3));
        cst = cst * sf + si * tj;
        float h = tanhf(cst) * so;

        // ---- publish: tag-in-data slots (fire-and-forget) + hint (no ack) ----
        {
            unsigned hu = (unsigned)__builtin_bit_cast(unsigned short, (f16)h);
            unsigned ot = __shfl_xor(hu, 16);          // partner dh^1
            if (do_st && t < T_ - 1) {
                unsigned dw = (hu & 0xffffu) | (ot << 16);   // [h(dh)][h(dh+1)]
                u64 val = (u64)dw | ((u64)(unsigned)(t + 2) << 32);
                __hip_atomic_store((u64*)(pay + (size_t)nxt * PAYB + st_off),
                                   val, __ATOMIC_RELAXED, __HIP_MEMORY_SCOPE_AGENT);
            }
        }
        if (l == 0 && t < T_ - 1)
            __hip_atomic_store(tag_st, (unsigned)(t + 2),
                               __ATOMIC_RELAXED, __HIP_MEMORY_SCOPE_AGENT);

        // out store off the critical path (non-temporal stream)
        __builtin_nontemporal_store(h, &out[((size_t)bglob * T_ + t) * N_ + nh]);

        __syncthreads();   // pacc anti-dependency for next step
        cur = nxt;
        nxt = (nxt == 2) ? 0 : nxt + 1;
    }
}

// ---------------------------------------------------------------------------
extern "C" void kernel_launch(void* const* d_in, const int* in_sizes, int n_in,
                              void* d_out, int out_size, void* d_ws, size_t ws_size,
                              hipStream_t stream) {
    const float* x    = (const float*)d_in[0];
    const float* W    = (const float*)d_in[1];
    const float* bias = (const float*)d_in[2];
    float* out = (float*)d_out;

    char* ws = (char*)d_ws;
    f16*  WxT = (f16*)ws;                         // [0,4MB), dead after k_xproj
    f16*  xp  = (f16*)(ws + ((size_t)4 << 20));   // 256 MB

    const size_t need = ((size_t)4 << 20) + ((size_t)1 << 28);
    if (ws_size < need) {
        hipMemsetAsync(d_out, 0, (size_t)out_size * sizeof(float), stream);
        return;
    }

    hipLaunchKernelGGL(k_transpose_wx, dim3(512), dim3(256), 0, stream, W, WxT);
    hipLaunchKernelGGL(k_xproj, dim3(512), dim3(256), 0, stream, x, WxT, bias, xp);

    // zero payload tags + hint tags (region overlaps dead WxT -> after xproj);
    // re-executes on every graph replay -> deterministic protocol start.
    hipMemsetAsync(ws, 0, 3 * PAYB + 4096, stream);

    const f16* xp_c = xp;
    void* args[] = { (void*)&W, (void*)&xp_c, (void*)&ws, (void*)&out };
    hipError_t e = hipLaunchCooperativeKernel((void*)k_recur9, dim3(256), dim3(256),
                                              args, 0, stream);
    if (e != hipSuccess) {
        // high-VGPR cooperative rejection (R2 ghost) -> normal launch;
        // grid 256 == CU count, 1 WG/CU: co-residency holds without coop.
        hipLaunchKernelGGL(k_recur9, dim3(256), dim3(256), 0, stream,
                           W, xp_c, ws, out);
    }
}

// Round 10
// 2018.537 us; speedup vs baseline: 1.1858x; 1.1858x over previous
//
#include <hip/hip_runtime.h>

#define B_ 64
#define T_ 512
#define D_ 512
#define N_ 1024
#define G_ 4096   // 4*N

typedef _Float16 f16;
typedef __attribute__((ext_vector_type(8))) _Float16 f16x8;
typedef __attribute__((ext_vector_type(4))) _Float16 f16x4;
typedef __attribute__((ext_vector_type(4))) float f32x4_t;
typedef unsigned long long u64;

static __device__ __forceinline__ f32x4_t mfma16(f16x8 a, f16x8 b, f32x4_t c) {
    return __builtin_amdgcn_mfma_f32_16x16x32_f16(a, b, c, 0, 0, 0);
}

// fast elementwise (serial critical path): sigmoid/tanh via v_exp-based __expf
static __device__ __forceinline__ float fsig(float x) {
    return 1.f / (1.f + __expf(-x));
}
static __device__ __forceinline__ float ftanh(float x) {
    return 1.f - 2.f / (__expf(2.f * x) + 1.f);   // exp->inf/0 limits correct
}

// workspace map (inside first 4MB, overlapping dead WxT)
#define PAYB   131072        // one payload copy: [bg4][32KB]
#define OFF_TAG 0x60000      // 3*PAYB; tags: 4*256 u32 = 4KB

// ---------------------------------------------------------------------------
// Phase 0: WxT[g][d] = (f16) W[d][g]   (validated R1)
// ---------------------------------------------------------------------------
__global__ __launch_bounds__(256) void k_transpose_wx(const float* __restrict__ W,
                                                      f16* __restrict__ WxT) {
    __shared__ float tile[64][65];
    int bx = blockIdx.x;
    int dt = bx >> 6, gt = bx & 63;
    int d0 = dt * 64, g0 = gt * 64;
    int tid = threadIdx.x;
    for (int e = tid; e < 4096; e += 256) {
        int r = e >> 6, c = e & 63;
        tile[r][c] = W[(size_t)(d0 + r) * G_ + (g0 + c)];
    }
    __syncthreads();
    for (int e = tid; e < 4096; e += 256) {
        int r = e >> 6, c = e & 63;
        WxT[(size_t)(g0 + r) * D_ + (d0 + c)] = (f16)tile[c][r];
    }
}

// ---------------------------------------------------------------------------
// Phase 1: xp[t][g][b] = (f16)( x@Wx + bias )   (validated R1)
// ---------------------------------------------------------------------------
__global__ __launch_bounds__(256, 2) void k_xproj(const float* __restrict__ x,
                                                  const f16* __restrict__ WxT,
                                                  const float* __restrict__ bias,
                                                  f16* __restrict__ xp) {
    __shared__ __align__(16) f16 alds[64 * 512];   // 64 KB
    int t = blockIdx.x;
    int tid = threadIdx.x;
    int w = tid >> 6, l = tid & 63;

    for (int ch = tid; ch < 4096; ch += 256) {
        int b  = ch >> 6;
        int d0 = (ch & 63) << 3;
        const float* px = x + ((size_t)b * T_ + t) * D_ + d0;
        float4 v0 = *(const float4*)px;
        float4 v1 = *(const float4*)(px + 4);
        f16x8 s;
        s[0] = (f16)v0.x; s[1] = (f16)v0.y; s[2] = (f16)v0.z; s[3] = (f16)v0.w;
        s[4] = (f16)v1.x; s[5] = (f16)v1.y; s[6] = (f16)v1.z; s[7] = (f16)v1.w;
        unsigned byteoff = ((unsigned)(b * 512 + d0) * 2u) ^ ((unsigned)(b & 7) << 4);
        *(f16x8*)((char*)alds + byteoff) = s;
    }
    __syncthreads();

    const int gw = w * 1024;
    const int qk = (l >> 4) << 3;
    const int cc = l & 15;

    for (int gtb = 0; gtb < 16; ++gtb) {
        f32x4_t acc[4][4];
        #pragma unroll
        for (int a = 0; a < 4; ++a)
            #pragma unroll
            for (int m = 0; m < 4; ++m) acc[a][m] = f32x4_t{0.f, 0.f, 0.f, 0.f};

        for (int ks = 0; ks < 16; ++ks) {
            f16x8 afr[4];
            #pragma unroll
            for (int mb = 0; mb < 4; ++mb) {
                int b = mb * 16 + cc;
                int d = ks * 32 + qk;
                unsigned byteoff = ((unsigned)(b * 512 + d) * 2u) ^ ((unsigned)(b & 7) << 4);
                afr[mb] = *(const f16x8*)((const char*)alds + byteoff);
            }
            #pragma unroll
            for (int gl = 0; gl < 4; ++gl) {
                int g = gw + (gtb * 4 + gl) * 16 + cc;
                f16x8 bfr = *(const f16x8*)(WxT + (size_t)g * D_ + ks * 32 + qk);
                #pragma unroll
                for (int mb = 0; mb < 4; ++mb)
                    acc[gl][mb] = mfma16(afr[mb], bfr, acc[gl][mb]);
            }
        }
        #pragma unroll
        for (int gl = 0; gl < 4; ++gl) {
            int g = gw + (gtb * 4 + gl) * 16 + cc;
            float bg = bias[g];
            #pragma unroll
            for (int mb = 0; mb < 4; ++mb) {
                int b0 = mb * 16 + ((l >> 4) << 2);
                f16x4 sv;
                sv[0] = (f16)(acc[gl][mb][0] + bg);
                sv[1] = (f16)(acc[gl][mb][1] + bg);
                sv[2] = (f16)(acc[gl][mb][2] + bg);
                sv[3] = (f16)(acc[gl][mb][3] + bg);
                *(f16x4*)(xp + ((size_t)t * G_ + g) * B_ + b0) = sv;
            }
        }
    }
}

// ---------------------------------------------------------------------------
// Phase 2: persistent recurrence = R8 protocol (validated, 1.85 ms) +
// Wh-in-registers (R9-validated numerics) + fast tanh on the serial path.
//  - payload: pure h slots (8B), TRIPLE-buffered.
//  - producer wave: 16 payload stores -> vmcnt(0) ack -> lane0 tag store.
//    (R9 lesson: the ack is what makes the tag meaningful - keep it.)
//  - consumer wave polls its 64 producer-wave tags (256B/round), then loads
//    payload exactly once.
// ---------------------------------------------------------------------------
__global__ __launch_bounds__(256, 1) void k_recur10(const float* __restrict__ W,
                                                    const f16* __restrict__ xp,
                                                    char* __restrict__ wsb,
                                                    float* __restrict__ out) {
    __shared__ float pacc[4][4][16][17];        // [kwave][ntile][batch][c15+pad]

    const int wg  = blockIdx.x;
    const int tid = threadIdx.x;
    const int w   = tid >> 6;
    const int l   = tid & 63;
    const int bg  = wg >> 6;
    const int ci  = wg & 63;

    const int lb    = l & 15;
    const int dh    = l >> 4;
    const int nh    = ci * 16 + w * 4 + dh;
    const int bglob = bg * 16 + lb;

    char*     const pay  = wsb;                      // 3 x 128 KB
    unsigned* const tags = (unsigned*)(wsb + OFF_TAG);

    // ---- Wh B-fragments into registers (mapping validated R3/R9) ----
    f16x8 bf[4][8];
    {
        const int kq = l >> 4, ty = (l >> 2) & 3, dcl = l & 3;
        #pragma unroll
        for (int nt = 0; nt < 4; ++nt) {
            const int gc = ty * 1024 + ci * 16 + nt * 4 + dcl;
            #pragma unroll
            for (int kk = 0; kk < 8; ++kk) {
                #pragma unroll
                for (int i = 0; i < 8; ++i) {
                    int k = (w * 8 + kk) * 32 + kq * 8 + i;
                    bf[nt][kk][i] = (f16)W[(size_t)(D_ + k) * G_ + gc];
                }
            }
        }
    }

    // ---- producer addressing (R8-validated pure-h slot layout) ----
    const int nq  = ci * 16 + w * 4;
    const int ksq = nq >> 5;
    const int q8  = (nq & 31) >> 3;
    const size_t st_off = (size_t)bg * 32768
                        + ((size_t)(ksq * 64 + q8 * 16 + lb) << 4)
                        + (size_t)(w & 1) * 8;
    const bool do_st = (dh == 0);

    // ---- consumer addressing: wave w reads k in [256w, 256w+256) ----
    const size_t ld_off = (size_t)bg * 32768 + ((size_t)(w * 8 * 64 + l) << 4);

    // tags: producer (ci, w) publishes; consumer lane l watches 64w+l
    unsigned* const tag_st = tags + (bg * 256 + ci * 4 + w);
    unsigned* const tag_ld = tags + (bg * 256 + w * 64 + l);

    // ---- init: zero payload buf0 (h_0 = 0), release, tag = 1 ----
    if (do_st)
        __hip_atomic_store((u64*)(pay + st_off), 0ull,
                           __ATOMIC_RELAXED, __HIP_MEMORY_SCOPE_AGENT);
    asm volatile("s_waitcnt vmcnt(0)" ::: "memory");
    if (l == 0)
        __hip_atomic_store(tag_st, 1u, __ATOMIC_RELAXED, __HIP_MEMORY_SCOPE_AGENT);

    __syncthreads();

    float cst = 0.f;
    int cur = 0, nxt = 1;

    for (int t = 0; t < T_; ++t) {
        // xp loads: non-temporal, issued early (HBM latency hides under poll)
        const unsigned short* xpp = (const unsigned short*)xp
                                  + (size_t)t * G_ * B_ + bglob;
        f16 xg0 = __builtin_bit_cast(f16, __builtin_nontemporal_load(xpp + (size_t)(0 * 1024 + nh) * B_));
        f16 xg1 = __builtin_bit_cast(f16, __builtin_nontemporal_load(xpp + (size_t)(1 * 1024 + nh) * B_));
        f16 xg2 = __builtin_bit_cast(f16, __builtin_nontemporal_load(xpp + (size_t)(2 * 1024 + nh) * B_));
        f16 xg3 = __builtin_bit_cast(f16, __builtin_nontemporal_load(xpp + (size_t)(3 * 1024 + nh) * B_));

        // ---- poll 64 producer-wave tags (256 B/wave/round) ----
        {
            const unsigned tgt = (unsigned)(t + 1);
            while (true) {
                unsigned v = __hip_atomic_load(tag_ld, __ATOMIC_RELAXED,
                                               __HIP_MEMORY_SCOPE_AGENT);
                if (__all(v >= tgt)) break;
                __builtin_amdgcn_s_sleep(1);
            }
        }

        // ---- payload: 8 x 16B coherent loads, once ----
        f16x8 af[8];
        {
            const char* pl = pay + (size_t)cur * PAYB + ld_off;
            #pragma unroll
            for (int kk = 0; kk < 8; ++kk)
                asm volatile("global_load_dwordx4 %0, %1, off sc0 sc1"
                             : "=&v"(af[kk]) : "v"(pl + kk * 1024) : "memory");
        }
        asm volatile("s_waitcnt vmcnt(0)" ::: "memory");
        __builtin_amdgcn_sched_barrier(0);   // rule 18: keep MFMA after the wait

        f32x4_t acc[4];
        #pragma unroll
        for (int nt = 0; nt < 4; ++nt) acc[nt] = f32x4_t{0.f, 0.f, 0.f, 0.f};
        #pragma unroll
        for (int kk = 0; kk < 8; ++kk) {
            #pragma unroll
            for (int nt = 0; nt < 4; ++nt)
                acc[nt] = mfma16(af[kk], bf[nt][kk], acc[nt]);
        }

        // ---- cross-wave K-reduction via LDS ----
        {
            const int r0 = dh << 2;
            #pragma unroll
            for (int nt = 0; nt < 4; ++nt)
                #pragma unroll
                for (int j = 0; j < 4; ++j)
                    pacc[w][nt][r0 + j][l & 15] = acc[nt][j];
        }
        __syncthreads();

        float g0 = pacc[0][w][lb][0 * 4 + dh] + pacc[1][w][lb][0 * 4 + dh]
                 + pacc[2][w][lb][0 * 4 + dh] + pacc[3][w][lb][0 * 4 + dh] + (float)xg0;
        float g1 = pacc[0][w][lb][1 * 4 + dh] + pacc[1][w][lb][1 * 4 + dh]
                 + pacc[2][w][lb][1 * 4 + dh] + pacc[3][w][lb][1 * 4 + dh] + (float)xg1;
        float g2 = pacc[0][w][lb][2 * 4 + dh] + pacc[1][w][lb][2 * 4 + dh]
                 + pacc[2][w][lb][2 * 4 + dh] + pacc[3][w][lb][2 * 4 + dh] + (float)xg2;
        float g3 = pacc[0][w][lb][3 * 4 + dh] + pacc[1][w][lb][3 * 4 + dh]
                 + pacc[2][w][lb][3 * 4 + dh] + pacc[3][w][lb][3 * 4 + dh] + (float)xg3;

        float si = fsig(g0);
        float tj = ftanh(g1);
        float sf = fsig(g2 + 1.f);
        float so = fsig(g3);
        cst = cst * sf + si * tj;
        float h = ftanh(cst) * so;

        // ---- publish: payload stores -> wave ack -> wave tag ----
        {
            unsigned hu = (unsigned)__builtin_bit_cast(unsigned short, (f16)h);
            unsigned ot = __shfl_xor(hu, 16);
            unsigned dw = (dh & 1) ? ((ot & 0xffffu) | (hu << 16))
                                   : ((hu & 0xffffu) | (ot << 16));
            unsigned dw2 = __shfl_xor(dw, 32);
            if (do_st && t < T_ - 1) {
                u64 val = (u64)dw | ((u64)dw2 << 32);
                __hip_atomic_store((u64*)(pay + (size_t)nxt * PAYB + st_off), val,
                                   __ATOMIC_RELAXED, __HIP_MEMORY_SCOPE_AGENT);
            }
        }
        asm volatile("s_waitcnt vmcnt(0)" ::: "memory");   // payload acked at LLC
        if (l == 0 && t < T_ - 1)
            __hip_atomic_store(tag_st, (unsigned)(t + 2),
                               __ATOMIC_RELAXED, __HIP_MEMORY_SCOPE_AGENT);

        // out store off the critical path (non-temporal stream)
        __builtin_nontemporal_store(h, &out[((size_t)bglob * T_ + t) * N_ + nh]);

        __syncthreads();   // pacc anti-dependency for next step
        cur = nxt;
        nxt = (nxt == 2) ? 0 : nxt + 1;
    }
}

// ---------------------------------------------------------------------------
extern "C" void kernel_launch(void* const* d_in, const int* in_sizes, int n_in,
                              void* d_out, int out_size, void* d_ws, size_t ws_size,
                              hipStream_t stream) {
    const float* x    = (const float*)d_in[0];
    const float* W    = (const float*)d_in[1];
    const float* bias = (const float*)d_in[2];
    float* out = (float*)d_out;

    char* ws = (char*)d_ws;
    f16*  WxT = (f16*)ws;                         // [0,4MB), dead after k_xproj
    f16*  xp  = (f16*)(ws + ((size_t)4 << 20));   // 256 MB

    const size_t need = ((size_t)4 << 20) + ((size_t)1 << 28);
    if (ws_size < need) {
        hipMemsetAsync(d_out, 0, (size_t)out_size * sizeof(float), stream);
        return;
    }

    hipLaunchKernelGGL(k_transpose_wx, dim3(512), dim3(256), 0, stream, W, WxT);
    hipLaunchKernelGGL(k_xproj, dim3(512), dim3(256), 0, stream, x, WxT, bias, xp);

    // zero the tag array (region overlaps dead WxT -> must run after k_xproj);
    // re-executes on every graph replay -> deterministic protocol start.
    hipMemsetAsync(ws + OFF_TAG, 0, 4096, stream);

    const f16* xp_c = xp;
    void* args[] = { (void*)&W, (void*)&xp_c, (void*)&ws, (void*)&out };
    hipError_t e = hipLaunchCooperativeKernel((void*)k_recur10, dim3(256), dim3(256),
                                              args, 0, stream);
    if (e != hipSuccess) {
        // high-VGPR cooperative rejection (R2 ghost) -> normal launch;
        // grid 256 == CU count, 1 WG/CU: co-residency holds without coop.
        hipLaunchKernelGGL(k_recur10, dim3(256), dim3(256), 0, stream,
                           W, xp_c, ws, out);
    }
}